// Round 4
// baseline (812.504 us; speedup 1.0000x reference)
//
#include <hip/hip_runtime.h>
#include <hip/hip_bf16.h>

#define T_ 4
#define N_ 50000
#define E_ 800000
#define C_ 128
#define K_ 3
#define TC_ 512           // T_*C_
#define UNROLL_ 8

typedef __hip_bfloat16 bf16;
typedef __attribute__((ext_vector_type(4))) float f32x4;
typedef __attribute__((ext_vector_type(8))) short bf16x8;
typedef __attribute__((ext_vector_type(4))) short s16x4;

__device__ inline short bf16bits(float f) {
    bf16 h = __float2bfloat16(f);
    union { bf16 h; short s; } u; u.h = h; return u.s;
}
__device__ inline float bf16f(short s) {
    union { bf16 h; short s; } u; u.s = s; return __bfloat162float(u.h);
}

// ---------------- CSR build ----------------

__global__ void count_kernel(const int* __restrict__ row, int* __restrict__ counts) {
    int e = blockIdx.x * blockDim.x + threadIdx.x;
    if (e < E_) atomicAdd(&counts[row[e]], 1);
}

__global__ __launch_bounds__(1024) void scan_kernel(const int* __restrict__ counts,
                                                    int* __restrict__ starts,
                                                    int* __restrict__ cursors) {
    __shared__ int wsum[16];
    __shared__ int carry_s;
    int tid = threadIdx.x;
    int wave = tid >> 6, lane = tid & 63;
    if (tid == 0) carry_s = 0;
    __syncthreads();
    for (int base = 0; base < N_; base += 1024) {
        int i = base + tid;
        int v = (i < N_) ? counts[i] : 0;
        int s = v;
        #pragma unroll
        for (int off = 1; off < 64; off <<= 1) {
            int u = __shfl_up(s, off, 64);
            if (lane >= off) s += u;
        }
        if (lane == 63) wsum[wave] = s;
        __syncthreads();
        if (wave == 0) {
            int w = (lane < 16) ? wsum[lane] : 0;
            #pragma unroll
            for (int off = 1; off < 16; off <<= 1) {
                int u = __shfl_up(w, off, 64);
                if (lane >= off) w += u;
            }
            if (lane < 16) wsum[lane] = w;
        }
        __syncthreads();
        int carry = carry_s;
        int wbase = (wave == 0) ? 0 : wsum[wave - 1];
        int incl = carry + wbase + s;
        if (i < N_) {
            starts[i]  = incl - v;
            cursors[i] = incl - v;
        }
        __syncthreads();
        if (tid == 1023) carry_s = incl;
        __syncthreads();
    }
    if (tid == 0) starts[N_] = carry_s;
}

__global__ void scatter_kernel(const int* __restrict__ row, const int* __restrict__ col,
                               const float* __restrict__ val, int* __restrict__ cursors,
                               int* __restrict__ scol, float* __restrict__ sval) {
    int e = blockIdx.x * blockDim.x + threadIdx.x;
    if (e < E_) {
        int p = atomicAdd(&cursors[row[e]], 1);
        scol[p] = col[e];
        sval[p] = val[e];
    }
}

// ---------------- convert: xb[n][t*C+c] = bf16(x[t][n][c]) ----------------
// grid: (N_*32/256, T_). Each thread one f32x4 quad.

__global__ __launch_bounds__(256) void convert_kernel(const float* __restrict__ x,
                                                      bf16* __restrict__ xb) {
    int t   = blockIdx.y;
    int idx = blockIdx.x * 256 + threadIdx.x;   // over N_*32
    int n = idx >> 5, q = idx & 31;
    f32x4 v = *(const f32x4*)(x + ((size_t)t * N_ + n) * C_ + q * 4);
    s16x4 o;
    #pragma unroll
    for (int j = 0; j < 4; ++j) o[j] = bf16bits(v[j]);
    *(s16x4*)(xb + (size_t)n * TC_ + t * C_ + q * 4) = o;
}

// ---------------- SpMM: dst[n][:] = sum_e val * src[col][:]   ([N][512] bf16, ILP-8) -------------
// 128 threads, thread tid owns channels [4*tid, 4*tid+4). One edge = contiguous 1 KB gather.

__global__ __launch_bounds__(128) void spmm_kernel(const int* __restrict__ starts,
                                                   const int* __restrict__ scol,
                                                   const float* __restrict__ sval,
                                                   const bf16* __restrict__ src,
                                                   bf16* __restrict__ dst) {
    int n   = blockIdx.x;
    int ch  = threadIdx.x * 4;
    int s  = starts[n];
    int e1 = starts[n + 1];
    const bf16* sb = src + ch;
    f32x4 acc = {0.f, 0.f, 0.f, 0.f};
    for (int e = s; e < e1; e += UNROLL_) {
        int   cc[UNROLL_];
        float vv[UNROLL_];
        #pragma unroll
        for (int j = 0; j < UNROLL_; ++j) {
            int ee = e + j;
            bool ok = ee < e1;
            cc[j] = ok ? scol[ee] : 0;
            vv[j] = ok ? sval[ee] : 0.f;
        }
        s16x4 g[UNROLL_];
        #pragma unroll
        for (int j = 0; j < UNROLL_; ++j)
            g[j] = *(const s16x4*)(sb + (size_t)cc[j] * TC_);
        #pragma unroll
        for (int j = 0; j < UNROLL_; ++j) {
            #pragma unroll
            for (int q = 0; q < 4; ++q)
                acc[q] += vv[j] * bf16f(g[j][q]);
        }
    }
    s16x4 o;
    #pragma unroll
    for (int j = 0; j < 4; ++j) o[j] = bf16bits(acc[j]);
    *(s16x4*)(dst + (size_t)n * TC_ + ch) = o;
}

// ---------------- GEMM: out[t] = X[t]@(W0-W2) + Tx1[t]@W1 + 2*U[t]@W2 + bias[t] -----------------
// A: sid0 = x (f32, [T][N][C]); sid1 = tx1b; sid2 = u  (bf16, [N][512], cols t*C..t*C+127)

__global__ __launch_bounds__(256) void gemm_kernel(const float* __restrict__ x,
                                                   const bf16* __restrict__ tx1b,
                                                   const bf16* __restrict__ ub,
                                                   const float* __restrict__ weight,
                                                   const float* __restrict__ bias,
                                                   float* __restrict__ out) {
    int t  = blockIdx.y;
    int m0 = blockIdx.x * 128;
    __shared__ short As[128][40];   // [row][k], +8 pad
    __shared__ short Bs[128][40];   // B^T: [n][k], +8 pad
    int tid  = threadIdx.x;
    int wave = tid >> 6, lane = tid & 63;
    int l15 = lane & 15, l4 = lane >> 4;

    f32x4 acc[2][8];
    for (int i = 0; i < 2; ++i)
        for (int j = 0; j < 8; ++j) acc[i][j] = (f32x4){0.f, 0.f, 0.f, 0.f};

    size_t tslice = (size_t)t * N_ * C_;

    for (int ks = 0; ks < 12; ++ks) {
        int sid = ks >> 2;
        int i0  = (ks & 3) * 32;
        // stage A tile: 128 rows x 32 k
        for (int slot = tid; slot < 512; slot += 256) {
            int r = slot >> 2, seg = slot & 3;
            int gr = m0 + r;
            int4 v = {0, 0, 0, 0};
            if (gr < N_) {
                if (sid == 0) {
                    const float* p = x + tslice + (size_t)gr * C_ + i0 + seg * 8;
                    union { int4 v; short s[8]; } u;
                    #pragma unroll
                    for (int j = 0; j < 8; ++j) u.s[j] = bf16bits(p[j]);
                    v = u.v;
                } else {
                    const bf16* p = (sid == 1 ? tx1b : ub) + (size_t)gr * TC_ + t * C_ + i0 + seg * 8;
                    v = *(const int4*)p;
                }
            }
            *(int4*)&As[r][seg * 8] = v;
        }
        // stage B^T tile with on-the-fly Chebyshev weight transform
        const float* W = weight + (((size_t)t * K_ + sid) * C_ + i0) * C_;
        for (int slot = tid; slot < 512; slot += 256) {
            int r = slot >> 4, seg = slot & 15;
            const float* p = W + (size_t)r * C_ + seg * 8;
            #pragma unroll
            for (int j = 0; j < 8; ++j) {
                float w;
                if (sid == 0)      w = p[j] - p[j + 2 * C_ * C_];  // W0 - W2
                else if (sid == 1) w = p[j];                        // W1
                else               w = 2.f * p[j];                  // 2*W2
                Bs[seg * 8 + j][r] = bf16bits(w);
            }
        }
        __syncthreads();

        int krow = l4 * 8;
        bf16x8 bfr[8];
        #pragma unroll
        for (int nf = 0; nf < 8; ++nf)
            bfr[nf] = *(bf16x8*)&Bs[nf * 16 + l15][krow];
        #pragma unroll
        for (int mf = 0; mf < 2; ++mf) {
            bf16x8 a = *(bf16x8*)&As[wave * 32 + mf * 16 + l15][krow];
            #pragma unroll
            for (int nf = 0; nf < 8; ++nf)
                acc[mf][nf] = __builtin_amdgcn_mfma_f32_16x16x32_bf16(a, bfr[nf], acc[mf][nf], 0, 0, 0);
        }
        __syncthreads();
    }

    const float* bs = bias + (size_t)t * C_;
    float* ot = out + tslice;
    #pragma unroll
    for (int nf = 0; nf < 8; ++nf) {
        int gc = nf * 16 + l15;
        float bv = bs[gc];
        #pragma unroll
        for (int mf = 0; mf < 2; ++mf) {
            #pragma unroll
            for (int reg = 0; reg < 4; ++reg) {
                int gr = m0 + wave * 32 + mf * 16 + l4 * 4 + reg;
                if (gr < N_) ot[(size_t)gr * C_ + gc] = acc[mf][nf][reg] + bv;
            }
        }
    }
}

// ---------------- launch ----------------

extern "C" void kernel_launch(void* const* d_in, const int* in_sizes, int n_in,
                              void* d_out, int out_size, void* d_ws, size_t ws_size,
                              hipStream_t stream) {
    const float* x      = (const float*)d_in[0];
    const int*   erow   = (const int*)d_in[1];
    const int*   ecol   = (const int*)d_in[2];
    const float* eval   = (const float*)d_in[3];
    const float* weight = (const float*)d_in[4];
    const float* bias   = (const float*)d_in[5];
    float* out = (float*)d_out;

    char* ws = (char*)d_ws;
    size_t off = 0;
    auto alloc = [&](size_t bytes) -> void* {
        void* p = ws + off;
        off += (bytes + 255) & ~(size_t)255;
        return p;
    };
    int*   counts  = (int*)alloc((N_ + 1) * sizeof(int));
    int*   starts  = (int*)alloc((N_ + 1) * sizeof(int));
    int*   cursors = (int*)alloc((size_t)N_ * sizeof(int));
    int*   scol    = (int*)alloc((size_t)E_ * sizeof(int));
    float* sval    = (float*)alloc((size_t)E_ * sizeof(float));
    bf16*  bufA    = (bf16*)alloc((size_t)N_ * TC_ * sizeof(bf16));  // xb, then U
    bf16*  bufB    = (bf16*)alloc((size_t)N_ * TC_ * sizeof(bf16));  // tx1

    hipMemsetAsync(counts, 0, (N_ + 1) * sizeof(int), stream);
    count_kernel<<<(E_ + 255) / 256, 256, 0, stream>>>(erow, counts);
    scan_kernel<<<1, 1024, 0, stream>>>(counts, starts, cursors);
    scatter_kernel<<<(E_ + 255) / 256, 256, 0, stream>>>(erow, ecol, eval, cursors, scol, sval);
    dim3 cg(N_ * 32 / 256, T_);
    convert_kernel<<<cg, 256, 0, stream>>>(x, bufA);                       // bufA = xb
    spmm_kernel<<<N_, 128, 0, stream>>>(starts, scol, sval, bufA, bufB);   // bufB = tx1 = S@x
    spmm_kernel<<<N_, 128, 0, stream>>>(starts, scol, sval, bufB, bufA);   // bufA = U = S@tx1
    dim3 g((N_ + 127) / 128, T_);
    gemm_kernel<<<g, 256, 0, stream>>>(x, bufB, bufA, weight, bias, out);
}

// Round 5
// 674.062 us; speedup vs baseline: 1.2054x; 1.2054x over previous
//
#include <hip/hip_runtime.h>
#include <hip/hip_bf16.h>

#define T_ 4
#define N_ 50000
#define E_ 800000
#define C_ 128
#define K_ 3
#define TC_ 512           // T_*C_
#define UNROLL_ 16

typedef __hip_bfloat16 bf16;
typedef __attribute__((ext_vector_type(4))) float f32x4;
typedef __attribute__((ext_vector_type(8))) short bf16x8;
typedef __attribute__((ext_vector_type(4))) short s16x4;

__device__ inline short bf16bits(float f) {
    bf16 h = __float2bfloat16(f);
    union { bf16 h; short s; } u; u.h = h; return u.s;
}
__device__ inline float bf16f(short s) {
    union { bf16 h; short s; } u; u.s = s; return __bfloat162float(u.h);
}

// ---------------- CSR build ----------------

__global__ void count_kernel(const int* __restrict__ row, int* __restrict__ counts) {
    int e = blockIdx.x * blockDim.x + threadIdx.x;
    if (e < E_) atomicAdd(&counts[row[e]], 1);
}

__global__ __launch_bounds__(1024) void scan_kernel(const int* __restrict__ counts,
                                                    int* __restrict__ starts,
                                                    int* __restrict__ cursors) {
    __shared__ int wsum[16];
    __shared__ int carry_s;
    int tid = threadIdx.x;
    int wave = tid >> 6, lane = tid & 63;
    if (tid == 0) carry_s = 0;
    __syncthreads();
    for (int base = 0; base < N_; base += 1024) {
        int i = base + tid;
        int v = (i < N_) ? counts[i] : 0;
        int s = v;
        #pragma unroll
        for (int off = 1; off < 64; off <<= 1) {
            int u = __shfl_up(s, off, 64);
            if (lane >= off) s += u;
        }
        if (lane == 63) wsum[wave] = s;
        __syncthreads();
        if (wave == 0) {
            int w = (lane < 16) ? wsum[lane] : 0;
            #pragma unroll
            for (int off = 1; off < 16; off <<= 1) {
                int u = __shfl_up(w, off, 64);
                if (lane >= off) w += u;
            }
            if (lane < 16) wsum[lane] = w;
        }
        __syncthreads();
        int carry = carry_s;
        int wbase = (wave == 0) ? 0 : wsum[wave - 1];
        int incl = carry + wbase + s;
        if (i < N_) {
            starts[i]  = incl - v;
            cursors[i] = incl - v;
        }
        __syncthreads();
        if (tid == 1023) carry_s = incl;
        __syncthreads();
    }
    if (tid == 0) starts[N_] = carry_s;
}

__global__ void scatter_kernel(const int* __restrict__ row, const int* __restrict__ col,
                               const float* __restrict__ val, int* __restrict__ cursors,
                               int* __restrict__ scol, float* __restrict__ sval) {
    int e = blockIdx.x * blockDim.x + threadIdx.x;
    if (e < E_) {
        int p = atomicAdd(&cursors[row[e]], 1);
        scol[p] = col[e];
        sval[p] = val[e];
    }
}

// ---------------- convert: xb[n][t*C+c] = bf16(x[t][n][c]) ----------------

__global__ __launch_bounds__(256) void convert_kernel(const float* __restrict__ x,
                                                      bf16* __restrict__ xb) {
    int t   = blockIdx.y;
    int idx = blockIdx.x * 256 + threadIdx.x;   // over N_*32
    int n = idx >> 5, q = idx & 31;
    f32x4 v = *(const f32x4*)(x + ((size_t)t * N_ + n) * C_ + q * 4);
    s16x4 o;
    #pragma unroll
    for (int j = 0; j < 4; ++j) o[j] = bf16bits(v[j]);
    *(s16x4*)(xb + (size_t)n * TC_ + t * C_ + q * 4) = o;
}

// ---------------- prep_w: Wt[t*3+kk][o][i] = bf16(cheb-transform(W[t][kk][i][o])) ---------------
// transform: kk0 -> W0 - W2; kk1 -> W1; kk2 -> 2*W2.  32x32 LDS tile transpose.

__global__ __launch_bounds__(256) void prep_w_kernel(const float* __restrict__ weight,
                                                     bf16* __restrict__ Wt) {
    __shared__ float lds[32][33];
    int b = blockIdx.x;
    int ts = b >> 4, tile = b & 15;
    int t = ts / 3, kk = ts % 3;
    int it = (tile >> 2) * 32, ot = (tile & 3) * 32;
    int tx = threadIdx.x & 31, ty = threadIdx.x >> 5;   // ty: 0..7
    const float* W  = weight + ((size_t)t * K_ + kk) * C_ * C_;
    const float* W2 = weight + ((size_t)t * K_ + 2) * C_ * C_;
    #pragma unroll
    for (int r = 0; r < 4; ++r) {
        int i = it + ty + r * 8, o = ot + tx;
        float w = W[(size_t)i * C_ + o];
        if (kk == 0)      w -= W2[(size_t)i * C_ + o];
        else if (kk == 2) w *= 2.f;
        lds[ty + r * 8][tx] = w;
    }
    __syncthreads();
    #pragma unroll
    for (int r = 0; r < 4; ++r) {
        int o = ot + ty + r * 8, i = it + tx;
        Wt[((size_t)ts * C_ + o) * C_ + i] = __float2bfloat16(lds[tx][ty + r * 8]);
    }
}

// ---------------- SpMM: dst[n][:] = sum_e val * src[col][:]   ([N][512] bf16, ILP-16) ------------

__global__ __launch_bounds__(128) void spmm_kernel(const int* __restrict__ starts,
                                                   const int* __restrict__ scol,
                                                   const float* __restrict__ sval,
                                                   const bf16* __restrict__ src,
                                                   bf16* __restrict__ dst) {
    int n   = blockIdx.x;
    int ch  = threadIdx.x * 4;
    int s  = starts[n];
    int e1 = starts[n + 1];
    const bf16* sb = src + ch;
    f32x4 acc = {0.f, 0.f, 0.f, 0.f};
    for (int e = s; e < e1; e += UNROLL_) {
        int   cc[UNROLL_];
        float vv[UNROLL_];
        #pragma unroll
        for (int j = 0; j < UNROLL_; ++j) {
            int ee = e + j;
            bool ok = ee < e1;
            cc[j] = ok ? scol[ee] : 0;
            vv[j] = ok ? sval[ee] : 0.f;
        }
        s16x4 g[UNROLL_];
        #pragma unroll
        for (int j = 0; j < UNROLL_; ++j)
            g[j] = *(const s16x4*)(sb + (size_t)cc[j] * TC_);
        #pragma unroll
        for (int j = 0; j < UNROLL_; ++j) {
            #pragma unroll
            for (int q = 0; q < 4; ++q)
                acc[q] += vv[j] * bf16f(g[j][q]);
        }
    }
    s16x4 o;
    #pragma unroll
    for (int j = 0; j < 4; ++j) o[j] = bf16bits(acc[j]);
    *(s16x4*)(dst + (size_t)n * TC_ + ch) = o;
}

// ---------------- GEMM (no LDS): out[t] = X[t]@(W0-W2) + Tx1[t]@W1 + 2*U[t]@W2 + bias[t] ---------
// 256 thr = 4 waves; wave owns rows m0+wave*32..+32, all 128 cols. Fragments straight from global.

__global__ __launch_bounds__(256) void gemm_kernel(const float* __restrict__ x,
                                                   const bf16* __restrict__ tx1b,
                                                   const bf16* __restrict__ ub,
                                                   const bf16* __restrict__ Wt,
                                                   const float* __restrict__ bias,
                                                   float* __restrict__ out) {
    int t  = blockIdx.y;
    int m0 = blockIdx.x * 128;
    int tid  = threadIdx.x;
    int wave = tid >> 6, lane = tid & 63;
    int l15 = lane & 15, l4 = lane >> 4;
    int krow = l4 * 8;

    f32x4 acc[2][8];
    #pragma unroll
    for (int i = 0; i < 2; ++i)
        #pragma unroll
        for (int j = 0; j < 8; ++j) acc[i][j] = (f32x4){0.f, 0.f, 0.f, 0.f};

    size_t tslice = (size_t)t * N_ * C_;
    int row[2];
    #pragma unroll
    for (int mf = 0; mf < 2; ++mf) {
        int gr = m0 + wave * 32 + mf * 16 + l15;
        row[mf] = gr < N_ ? gr : N_ - 1;
    }
    const bf16* wt = Wt + (size_t)t * 3 * C_ * C_;   // [3][o=128][k=128]

    #pragma unroll
    for (int sid = 0; sid < 3; ++sid) {
        #pragma unroll
        for (int kk = 0; kk < 4; ++kk) {
            int i0 = kk * 32;
            const bf16* wb = wt + (size_t)sid * C_ * C_ + i0 + krow;
            bf16x8 bfr[8];
            #pragma unroll
            for (int nf = 0; nf < 8; ++nf)
                bfr[nf] = *(const bf16x8*)(wb + (size_t)(nf * 16 + l15) * C_);
            bf16x8 a[2];
            if (sid == 0) {
                #pragma unroll
                for (int mf = 0; mf < 2; ++mf) {
                    const float* p = x + tslice + (size_t)row[mf] * C_ + i0 + krow;
                    f32x4 u0 = *(const f32x4*)p;
                    f32x4 u1 = *(const f32x4*)(p + 4);
                    bf16x8 av;
                    #pragma unroll
                    for (int j = 0; j < 4; ++j) { av[j] = bf16bits(u0[j]); av[j + 4] = bf16bits(u1[j]); }
                    a[mf] = av;
                }
            } else {
                const bf16* src = (sid == 1) ? tx1b : ub;
                #pragma unroll
                for (int mf = 0; mf < 2; ++mf)
                    a[mf] = *(const bf16x8*)(src + (size_t)row[mf] * TC_ + t * C_ + i0 + krow);
            }
            #pragma unroll
            for (int mf = 0; mf < 2; ++mf)
                #pragma unroll
                for (int nf = 0; nf < 8; ++nf)
                    acc[mf][nf] = __builtin_amdgcn_mfma_f32_16x16x32_bf16(a[mf], bfr[nf], acc[mf][nf], 0, 0, 0);
        }
    }

    const float* bs = bias + (size_t)t * C_;
    float* ot = out + tslice;
    #pragma unroll
    for (int nf = 0; nf < 8; ++nf) {
        int gc = nf * 16 + l15;
        float bv = bs[gc];
        #pragma unroll
        for (int mf = 0; mf < 2; ++mf) {
            #pragma unroll
            for (int reg = 0; reg < 4; ++reg) {
                int gr = m0 + wave * 32 + mf * 16 + l4 * 4 + reg;
                if (gr < N_) ot[(size_t)gr * C_ + gc] = acc[mf][nf][reg] + bv;
            }
        }
    }
}

// ---------------- launch ----------------

extern "C" void kernel_launch(void* const* d_in, const int* in_sizes, int n_in,
                              void* d_out, int out_size, void* d_ws, size_t ws_size,
                              hipStream_t stream) {
    const float* x      = (const float*)d_in[0];
    const int*   erow   = (const int*)d_in[1];
    const int*   ecol   = (const int*)d_in[2];
    const float* eval   = (const float*)d_in[3];
    const float* weight = (const float*)d_in[4];
    const float* bias   = (const float*)d_in[5];
    float* out = (float*)d_out;

    char* ws = (char*)d_ws;
    size_t off = 0;
    auto alloc = [&](size_t bytes) -> void* {
        void* p = ws + off;
        off += (bytes + 255) & ~(size_t)255;
        return p;
    };
    int*   counts  = (int*)alloc((N_ + 1) * sizeof(int));
    int*   starts  = (int*)alloc((N_ + 1) * sizeof(int));
    int*   cursors = (int*)alloc((size_t)N_ * sizeof(int));
    int*   scol    = (int*)alloc((size_t)E_ * sizeof(int));
    float* sval    = (float*)alloc((size_t)E_ * sizeof(float));
    bf16*  bufA    = (bf16*)alloc((size_t)N_ * TC_ * sizeof(bf16));  // xb, then U
    bf16*  bufB    = (bf16*)alloc((size_t)N_ * TC_ * sizeof(bf16));  // tx1
    bf16*  Wt      = (bf16*)alloc((size_t)T_ * K_ * C_ * C_ * sizeof(bf16));

    hipMemsetAsync(counts, 0, (N_ + 1) * sizeof(int), stream);
    count_kernel<<<(E_ + 255) / 256, 256, 0, stream>>>(erow, counts);
    scan_kernel<<<1, 1024, 0, stream>>>(counts, starts, cursors);
    scatter_kernel<<<(E_ + 255) / 256, 256, 0, stream>>>(erow, ecol, eval, cursors, scol, sval);
    prep_w_kernel<<<T_ * K_ * 16, 256, 0, stream>>>(weight, Wt);
    dim3 cg(N_ * 32 / 256, T_);
    convert_kernel<<<cg, 256, 0, stream>>>(x, bufA);                       // bufA = xb
    spmm_kernel<<<N_, 128, 0, stream>>>(starts, scol, sval, bufA, bufB);   // bufB = tx1 = S@x
    spmm_kernel<<<N_, 128, 0, stream>>>(starts, scol, sval, bufB, bufA);   // bufA = U = S@tx1
    dim3 g((N_ + 127) / 128, T_);
    gemm_kernel<<<g, 256, 0, stream>>>(x, bufB, bufA, Wt, bias, out);
}

// Round 6
// 657.951 us; speedup vs baseline: 1.2349x; 1.0245x over previous
//
#include <hip/hip_runtime.h>
#include <hip/hip_bf16.h>

#define T_ 4
#define N_ 50000
#define E_ 800000
#define C_ 128
#define K_ 3
#define TC_ 512           // T_*C_
#define UNROLL_ 16
#define GROWS_ 256        // rows per GEMM block

typedef __hip_bfloat16 bf16;
typedef __attribute__((ext_vector_type(4))) float f32x4;
typedef __attribute__((ext_vector_type(8))) short bf16x8;
typedef __attribute__((ext_vector_type(4))) short s16x4;

__device__ inline short bf16bits(float f) {
    bf16 h = __float2bfloat16(f);
    union { bf16 h; short s; } u; u.h = h; return u.s;
}
__device__ inline float bf16f(short s) {
    union { bf16 h; short s; } u; u.s = s; return __bfloat162float(u.h);
}

// ---------------- CSR build ----------------

__global__ void count_kernel(const int* __restrict__ row, int* __restrict__ counts) {
    int e = blockIdx.x * blockDim.x + threadIdx.x;
    if (e < E_) atomicAdd(&counts[row[e]], 1);
}

__global__ __launch_bounds__(1024) void scan_kernel(const int* __restrict__ counts,
                                                    int* __restrict__ starts,
                                                    int* __restrict__ cursors) {
    __shared__ int wsum[16];
    __shared__ int carry_s;
    int tid = threadIdx.x;
    int wave = tid >> 6, lane = tid & 63;
    if (tid == 0) carry_s = 0;
    __syncthreads();
    for (int base = 0; base < N_; base += 1024) {
        int i = base + tid;
        int v = (i < N_) ? counts[i] : 0;
        int s = v;
        #pragma unroll
        for (int off = 1; off < 64; off <<= 1) {
            int u = __shfl_up(s, off, 64);
            if (lane >= off) s += u;
        }
        if (lane == 63) wsum[wave] = s;
        __syncthreads();
        if (wave == 0) {
            int w = (lane < 16) ? wsum[lane] : 0;
            #pragma unroll
            for (int off = 1; off < 16; off <<= 1) {
                int u = __shfl_up(w, off, 64);
                if (lane >= off) w += u;
            }
            if (lane < 16) wsum[lane] = w;
        }
        __syncthreads();
        int carry = carry_s;
        int wbase = (wave == 0) ? 0 : wsum[wave - 1];
        int incl = carry + wbase + s;
        if (i < N_) {
            starts[i]  = incl - v;
            cursors[i] = incl - v;
        }
        __syncthreads();
        if (tid == 1023) carry_s = incl;
        __syncthreads();
    }
    if (tid == 0) starts[N_] = carry_s;
}

__global__ void scatter_kernel(const int* __restrict__ row, const int* __restrict__ col,
                               const float* __restrict__ val, int* __restrict__ cursors,
                               int* __restrict__ scol, float* __restrict__ sval) {
    int e = blockIdx.x * blockDim.x + threadIdx.x;
    if (e < E_) {
        int p = atomicAdd(&cursors[row[e]], 1);
        scol[p] = col[e];
        sval[p] = val[e];
    }
}

// ---------------- convert: xb[n][t*C+c] = bf16(x[t][n][c]) ----------------

__global__ __launch_bounds__(256) void convert_kernel(const float* __restrict__ x,
                                                      bf16* __restrict__ xb) {
    int t   = blockIdx.y;
    int idx = blockIdx.x * 256 + threadIdx.x;   // over N_*32
    int n = idx >> 5, q = idx & 31;
    f32x4 v = *(const f32x4*)(x + ((size_t)t * N_ + n) * C_ + q * 4);
    s16x4 o;
    #pragma unroll
    for (int j = 0; j < 4; ++j) o[j] = bf16bits(v[j]);
    *(s16x4*)(xb + (size_t)n * TC_ + t * C_ + q * 4) = o;
}

// ---------------- prep_w: Wt[t*3+kk][o][i] = bf16(cheb-transform(W[t][kk][i][o])) ---------------

__global__ __launch_bounds__(256) void prep_w_kernel(const float* __restrict__ weight,
                                                     bf16* __restrict__ Wt) {
    __shared__ float lds[32][33];
    int b = blockIdx.x;
    int ts = b >> 4, tile = b & 15;
    int t = ts / 3, kk = ts % 3;
    int it = (tile >> 2) * 32, ot = (tile & 3) * 32;
    int tx = threadIdx.x & 31, ty = threadIdx.x >> 5;   // ty: 0..7
    const float* W  = weight + ((size_t)t * K_ + kk) * C_ * C_;
    const float* W2 = weight + ((size_t)t * K_ + 2) * C_ * C_;
    #pragma unroll
    for (int r = 0; r < 4; ++r) {
        int i = it + ty + r * 8, o = ot + tx;
        float w = W[(size_t)i * C_ + o];
        if (kk == 0)      w -= W2[(size_t)i * C_ + o];
        else if (kk == 2) w *= 2.f;
        lds[ty + r * 8][tx] = w;
    }
    __syncthreads();
    #pragma unroll
    for (int r = 0; r < 4; ++r) {
        int o = ot + ty + r * 8, i = it + tx;
        Wt[((size_t)ts * C_ + o) * C_ + i] = __float2bfloat16(lds[tx][ty + r * 8]);
    }
}

// ---------------- SpMM: dst[n][:] = sum_e val * src[col][:]   ([N][512] bf16, ILP-16) ------------

__global__ __launch_bounds__(128) void spmm_kernel(const int* __restrict__ starts,
                                                   const int* __restrict__ scol,
                                                   const float* __restrict__ sval,
                                                   const bf16* __restrict__ src,
                                                   bf16* __restrict__ dst) {
    int n   = blockIdx.x;
    int ch  = threadIdx.x * 4;
    int s  = starts[n];
    int e1 = starts[n + 1];
    const bf16* sb = src + ch;
    f32x4 acc = {0.f, 0.f, 0.f, 0.f};
    for (int e = s; e < e1; e += UNROLL_) {
        int   cc[UNROLL_];
        float vv[UNROLL_];
        #pragma unroll
        for (int j = 0; j < UNROLL_; ++j) {
            int ee = e + j;
            bool ok = ee < e1;
            cc[j] = ok ? scol[ee] : 0;
            vv[j] = ok ? sval[ee] : 0.f;
        }
        s16x4 g[UNROLL_];
        #pragma unroll
        for (int j = 0; j < UNROLL_; ++j)
            g[j] = *(const s16x4*)(sb + (size_t)cc[j] * TC_);
        #pragma unroll
        for (int j = 0; j < UNROLL_; ++j) {
            #pragma unroll
            for (int q = 0; q < 4; ++q)
                acc[q] += vv[j] * bf16f(g[j][q]);
        }
    }
    s16x4 o;
    #pragma unroll
    for (int j = 0; j < 4; ++j) o[j] = bf16bits(acc[j]);
    *(s16x4*)(dst + (size_t)n * TC_ + ch) = o;
}

// ---------------- GEMM v3: LDS-staged B panel, 512 thr / 256 rows per block ----------------------
// out[t] = X[t]@(W0-W2) + Tx1[t]@W1 + 2*U[t]@W2 + bias[t]
// B panel per sid: 128x128 bf16 = 32 KB, staged regs->LDS (issue-early/write-late).
// LDS rows padded to 136 shorts (272 B = 17*16): ds_read_b128 conflict-free (2-way max).

__global__ __launch_bounds__(512) void gemm_kernel(const float* __restrict__ x,
                                                   const bf16* __restrict__ tx1b,
                                                   const bf16* __restrict__ ub,
                                                   const bf16* __restrict__ Wt,
                                                   const float* __restrict__ bias,
                                                   float* __restrict__ out) {
    __shared__ __align__(16) short Bs[128][136];
    int t  = blockIdx.y;
    int m0 = blockIdx.x * GROWS_;
    int tid  = threadIdx.x;
    int wave = tid >> 6, lane = tid & 63;
    int l15 = lane & 15, l4 = lane >> 4;
    int krow = l4 * 8;

    // staging coords: thread stages one 16B slot per iter; 4 iters cover 128x128
    int sr = tid >> 4;            // 0..31: row within 32-row group
    int ss = (tid & 15) * 8;      // slot start (elements)

    f32x4 acc[2][8];
    #pragma unroll
    for (int i = 0; i < 2; ++i)
        #pragma unroll
        for (int j = 0; j < 8; ++j) acc[i][j] = (f32x4){0.f, 0.f, 0.f, 0.f};

    size_t tslice = (size_t)t * N_ * C_;
    int row[2];
    #pragma unroll
    for (int mf = 0; mf < 2; ++mf) {
        int gr = m0 + wave * 32 + mf * 16 + l15;
        row[mf] = gr < N_ ? gr : N_ - 1;
    }
    const bf16* wt = Wt + (size_t)t * 3 * C_ * C_;   // [3][o=128][k=128]

    // stage sid0 panel
    int4 pf[4];
    #pragma unroll
    for (int i = 0; i < 4; ++i)
        pf[i] = *(const int4*)(wt + (size_t)(i * 32 + sr) * C_ + ss);
    #pragma unroll
    for (int i = 0; i < 4; ++i)
        *(int4*)&Bs[i * 32 + sr][ss] = pf[i];
    __syncthreads();

    #pragma unroll
    for (int sid = 0; sid < 3; ++sid) {
        // issue next panel's global loads early (hide under MFMAs below)
        if (sid < 2) {
            const bf16* wn = wt + (size_t)(sid + 1) * C_ * C_;
            #pragma unroll
            for (int i = 0; i < 4; ++i)
                pf[i] = *(const int4*)(wn + (size_t)(i * 32 + sr) * C_ + ss);
        }
        #pragma unroll
        for (int kk = 0; kk < 4; ++kk) {
            int i0 = kk * 32;
            bf16x8 bfr[8];
            #pragma unroll
            for (int nf = 0; nf < 8; ++nf)
                bfr[nf] = *(bf16x8*)&Bs[nf * 16 + l15][i0 + krow];
            bf16x8 a[2];
            if (sid == 0) {
                #pragma unroll
                for (int mf = 0; mf < 2; ++mf) {
                    const float* p = x + tslice + (size_t)row[mf] * C_ + i0 + krow;
                    f32x4 u0 = *(const f32x4*)p;
                    f32x4 u1 = *(const f32x4*)(p + 4);
                    bf16x8 av;
                    #pragma unroll
                    for (int j = 0; j < 4; ++j) { av[j] = bf16bits(u0[j]); av[j + 4] = bf16bits(u1[j]); }
                    a[mf] = av;
                }
            } else {
                const bf16* src = (sid == 1) ? tx1b : ub;
                #pragma unroll
                for (int mf = 0; mf < 2; ++mf)
                    a[mf] = *(const bf16x8*)(src + (size_t)row[mf] * TC_ + t * C_ + i0 + krow);
            }
            #pragma unroll
            for (int mf = 0; mf < 2; ++mf)
                #pragma unroll
                for (int nf = 0; nf < 8; ++nf)
                    acc[mf][nf] = __builtin_amdgcn_mfma_f32_16x16x32_bf16(a[mf], bfr[nf], acc[mf][nf], 0, 0, 0);
        }
        __syncthreads();
        if (sid < 2) {
            #pragma unroll
            for (int i = 0; i < 4; ++i)
                *(int4*)&Bs[i * 32 + sr][ss] = pf[i];
            __syncthreads();
        }
    }

    const float* bs = bias + (size_t)t * C_;
    float* ot = out + tslice;
    #pragma unroll
    for (int nf = 0; nf < 8; ++nf) {
        int gc = nf * 16 + l15;
        float bv = bs[gc];
        #pragma unroll
        for (int mf = 0; mf < 2; ++mf) {
            #pragma unroll
            for (int reg = 0; reg < 4; ++reg) {
                int gr = m0 + wave * 32 + mf * 16 + l4 * 4 + reg;
                if (gr < N_) ot[(size_t)gr * C_ + gc] = acc[mf][nf][reg] + bv;
            }
        }
    }
}

// ---------------- launch ----------------

extern "C" void kernel_launch(void* const* d_in, const int* in_sizes, int n_in,
                              void* d_out, int out_size, void* d_ws, size_t ws_size,
                              hipStream_t stream) {
    const float* x      = (const float*)d_in[0];
    const int*   erow   = (const int*)d_in[1];
    const int*   ecol   = (const int*)d_in[2];
    const float* eval   = (const float*)d_in[3];
    const float* weight = (const float*)d_in[4];
    const float* bias   = (const float*)d_in[5];
    float* out = (float*)d_out;

    char* ws = (char*)d_ws;
    size_t off = 0;
    auto alloc = [&](size_t bytes) -> void* {
        void* p = ws + off;
        off += (bytes + 255) & ~(size_t)255;
        return p;
    };
    int*   counts  = (int*)alloc((N_ + 1) * sizeof(int));
    int*   starts  = (int*)alloc((N_ + 1) * sizeof(int));
    int*   cursors = (int*)alloc((size_t)N_ * sizeof(int));
    int*   scol    = (int*)alloc((size_t)E_ * sizeof(int));
    float* sval    = (float*)alloc((size_t)E_ * sizeof(float));
    bf16*  bufA    = (bf16*)alloc((size_t)N_ * TC_ * sizeof(bf16));  // xb, then U
    bf16*  bufB    = (bf16*)alloc((size_t)N_ * TC_ * sizeof(bf16));  // tx1
    bf16*  Wt      = (bf16*)alloc((size_t)T_ * K_ * C_ * C_ * sizeof(bf16));

    hipMemsetAsync(counts, 0, (N_ + 1) * sizeof(int), stream);
    count_kernel<<<(E_ + 255) / 256, 256, 0, stream>>>(erow, counts);
    scan_kernel<<<1, 1024, 0, stream>>>(counts, starts, cursors);
    scatter_kernel<<<(E_ + 255) / 256, 256, 0, stream>>>(erow, ecol, eval, cursors, scol, sval);
    prep_w_kernel<<<T_ * K_ * 16, 256, 0, stream>>>(weight, Wt);
    dim3 cg(N_ * 32 / 256, T_);
    convert_kernel<<<cg, 256, 0, stream>>>(x, bufA);                       // bufA = xb
    spmm_kernel<<<N_, 128, 0, stream>>>(starts, scol, sval, bufA, bufB);   // bufB = tx1 = S@x
    spmm_kernel<<<N_, 128, 0, stream>>>(starts, scol, sval, bufB, bufA);   // bufA = U = S@tx1
    dim3 g((N_ + GROWS_ - 1) / GROWS_, T_);
    gemm_kernel<<<g, 512, 0, stream>>>(x, bufB, bufA, Wt, bias, out);
}

// Round 7
// 627.587 us; speedup vs baseline: 1.2946x; 1.0484x over previous
//
#include <hip/hip_runtime.h>
#include <hip/hip_bf16.h>

#define T_ 4
#define N_ 50000
#define E_ 800000
#define C_ 128
#define K_ 3
#define TC_ 512           // T_*C_
#define UNROLL_ 16
#define GROWS_ 256        // rows per GEMM block

typedef __hip_bfloat16 bf16;
typedef __attribute__((ext_vector_type(4))) float f32x4;
typedef __attribute__((ext_vector_type(8))) short bf16x8;
typedef __attribute__((ext_vector_type(4))) short s16x4;

__device__ inline short bf16bits(float f) {
    bf16 h = __float2bfloat16(f);
    union { bf16 h; short s; } u; u.h = h; return u.s;
}
__device__ inline float bf16f(short s) {
    union { bf16 h; short s; } u; u.s = s; return __bfloat162float(u.h);
}

// ---------------- CSR build ----------------

__global__ void count_kernel(const int* __restrict__ row, int* __restrict__ counts) {
    int i = (blockIdx.x * blockDim.x + threadIdx.x) * 4;
    if (i + 3 < E_) {
        int4 r = *(const int4*)(row + i);
        atomicAdd(&counts[r.x], 1);
        atomicAdd(&counts[r.y], 1);
        atomicAdd(&counts[r.z], 1);
        atomicAdd(&counts[r.w], 1);
    } else {
        for (int j = i; j < E_; ++j) atomicAdd(&counts[row[j]], 1);
    }
}

__global__ __launch_bounds__(1024) void scan_kernel(const int* __restrict__ counts,
                                                    int* __restrict__ starts,
                                                    int* __restrict__ cursors) {
    __shared__ int wsum[16];
    __shared__ int carry_s;
    int tid = threadIdx.x;
    int wave = tid >> 6, lane = tid & 63;
    if (tid == 0) carry_s = 0;
    __syncthreads();
    for (int base = 0; base < N_; base += 1024) {
        int i = base + tid;
        int v = (i < N_) ? counts[i] : 0;
        int s = v;
        #pragma unroll
        for (int off = 1; off < 64; off <<= 1) {
            int u = __shfl_up(s, off, 64);
            if (lane >= off) s += u;
        }
        if (lane == 63) wsum[wave] = s;
        __syncthreads();
        if (wave == 0) {
            int w = (lane < 16) ? wsum[lane] : 0;
            #pragma unroll
            for (int off = 1; off < 16; off <<= 1) {
                int u = __shfl_up(w, off, 64);
                if (lane >= off) w += u;
            }
            if (lane < 16) wsum[lane] = w;
        }
        __syncthreads();
        int carry = carry_s;
        int wbase = (wave == 0) ? 0 : wsum[wave - 1];
        int incl = carry + wbase + s;
        if (i < N_) {
            starts[i]  = incl - v;
            cursors[i] = incl - v;
        }
        __syncthreads();
        if (tid == 1023) carry_s = incl;
        __syncthreads();
    }
    if (tid == 0) starts[N_] = carry_s;
}

__global__ void scatter_kernel(const int* __restrict__ row, const int* __restrict__ col,
                               const float* __restrict__ val, int* __restrict__ cursors,
                               int2* __restrict__ packed) {
    int i = (blockIdx.x * blockDim.x + threadIdx.x) * 2;
    if (i < E_) {
        int2   r = *(const int2*)(row + i);
        int2   c = *(const int2*)(col + i);
        float2 v = *(const float2*)(val + i);
        int p0 = atomicAdd(&cursors[r.x], 1);
        packed[p0] = make_int2(c.x, __float_as_int(v.x));
        int p1 = atomicAdd(&cursors[r.y], 1);
        packed[p1] = make_int2(c.y, __float_as_int(v.y));
    }
}

// ---------------- convert: xb[n][t*C+c] = bf16(x[t][n][c]) ----------------

__global__ __launch_bounds__(256) void convert_kernel(const float* __restrict__ x,
                                                      bf16* __restrict__ xb) {
    int t   = blockIdx.y;
    int idx = blockIdx.x * 256 + threadIdx.x;   // over N_*32
    int n = idx >> 5, q = idx & 31;
    f32x4 v = *(const f32x4*)(x + ((size_t)t * N_ + n) * C_ + q * 4);
    s16x4 o;
    #pragma unroll
    for (int j = 0; j < 4; ++j) o[j] = bf16bits(v[j]);
    *(s16x4*)(xb + (size_t)n * TC_ + t * C_ + q * 4) = o;
}

// ---------------- prep_w: Wt[t*3+kk][o][i] = bf16(cheb-transform(W[t][kk][i][o])) ---------------

__global__ __launch_bounds__(256) void prep_w_kernel(const float* __restrict__ weight,
                                                     bf16* __restrict__ Wt) {
    __shared__ float lds[32][33];
    int b = blockIdx.x;
    int ts = b >> 4, tile = b & 15;
    int t = ts / 3, kk = ts % 3;
    int it = (tile >> 2) * 32, ot = (tile & 3) * 32;
    int tx = threadIdx.x & 31, ty = threadIdx.x >> 5;   // ty: 0..7
    const float* W  = weight + ((size_t)t * K_ + kk) * C_ * C_;
    const float* W2 = weight + ((size_t)t * K_ + 2) * C_ * C_;
    #pragma unroll
    for (int r = 0; r < 4; ++r) {
        int i = it + ty + r * 8, o = ot + tx;
        float w = W[(size_t)i * C_ + o];
        if (kk == 0)      w -= W2[(size_t)i * C_ + o];
        else if (kk == 2) w *= 2.f;
        lds[ty + r * 8][tx] = w;
    }
    __syncthreads();
    #pragma unroll
    for (int r = 0; r < 4; ++r) {
        int o = ot + ty + r * 8, i = it + tx;
        Wt[((size_t)ts * C_ + o) * C_ + i] = __float2bfloat16(lds[tx][ty + r * 8]);
    }
}

// ---------------- SpMM: dst[n][:] = sum_e val * src[col][:]   ([N][512] bf16, ILP-16) ------------

__global__ __launch_bounds__(128) void spmm_kernel(const int* __restrict__ starts,
                                                   const int2* __restrict__ packed,
                                                   const bf16* __restrict__ src,
                                                   bf16* __restrict__ dst) {
    int n   = blockIdx.x;
    int ch  = threadIdx.x * 4;
    int s  = starts[n];
    int e1 = starts[n + 1];
    const bf16* sb = src + ch;
    f32x4 acc = {0.f, 0.f, 0.f, 0.f};
    for (int e = s; e < e1; e += UNROLL_) {
        int2 ev[UNROLL_];
        #pragma unroll
        for (int j = 0; j < UNROLL_; ++j) {
            int ee = e + j;
            ev[j] = (ee < e1) ? packed[ee] : make_int2(0, 0);
        }
        s16x4 g[UNROLL_];
        #pragma unroll
        for (int j = 0; j < UNROLL_; ++j)
            g[j] = *(const s16x4*)(sb + (size_t)ev[j].x * TC_);
        #pragma unroll
        for (int j = 0; j < UNROLL_; ++j) {
            float v = __int_as_float(ev[j].y);
            #pragma unroll
            for (int q = 0; q < 4; ++q)
                acc[q] += v * bf16f(g[j][q]);
        }
    }
    s16x4 o;
    #pragma unroll
    for (int j = 0; j < 4; ++j) o[j] = bf16bits(acc[j]);
    *(s16x4*)(dst + (size_t)n * TC_ + ch) = o;
}

// ---------------- GEMM: LDS-staged B panel, 512 thr / 256 rows per block -------------------------
// out[t] = X[t]@(W0-W2) + Tx1[t]@W1 + 2*U[t]@W2 + bias[t]
// XBF16=1: A read from xb/tx1/u, all bf16 [N][512].  XBF16=0: sid0 reads f32 x + converts.

template <int XBF16>
__global__ __launch_bounds__(512) void gemm_kernel(const float* __restrict__ x,
                                                   const bf16* __restrict__ xb,
                                                   const bf16* __restrict__ tx1b,
                                                   const bf16* __restrict__ ub,
                                                   const bf16* __restrict__ Wt,
                                                   const float* __restrict__ bias,
                                                   float* __restrict__ out) {
    __shared__ __align__(16) short Bs[128][136];
    int t  = blockIdx.y;
    int m0 = blockIdx.x * GROWS_;
    int tid  = threadIdx.x;
    int wave = tid >> 6, lane = tid & 63;
    int l15 = lane & 15, l4 = lane >> 4;
    int krow = l4 * 8;

    int sr = tid >> 4;            // 0..31: row within 32-row group
    int ss = (tid & 15) * 8;      // slot start (elements)

    f32x4 acc[2][8];
    #pragma unroll
    for (int i = 0; i < 2; ++i)
        #pragma unroll
        for (int j = 0; j < 8; ++j) acc[i][j] = (f32x4){0.f, 0.f, 0.f, 0.f};

    size_t tslice = (size_t)t * N_ * C_;
    int row[2];
    #pragma unroll
    for (int mf = 0; mf < 2; ++mf) {
        int gr = m0 + wave * 32 + mf * 16 + l15;
        row[mf] = gr < N_ ? gr : N_ - 1;
    }
    const bf16* wt = Wt + (size_t)t * 3 * C_ * C_;   // [3][o=128][k=128]

    // stage sid0 panel
    int4 pf[4];
    #pragma unroll
    for (int i = 0; i < 4; ++i)
        pf[i] = *(const int4*)(wt + (size_t)(i * 32 + sr) * C_ + ss);
    #pragma unroll
    for (int i = 0; i < 4; ++i)
        *(int4*)&Bs[i * 32 + sr][ss] = pf[i];
    __syncthreads();

    #pragma unroll
    for (int sid = 0; sid < 3; ++sid) {
        // issue next panel's global loads early (hide under MFMAs below)
        if (sid < 2) {
            const bf16* wn = wt + (size_t)(sid + 1) * C_ * C_;
            #pragma unroll
            for (int i = 0; i < 4; ++i)
                pf[i] = *(const int4*)(wn + (size_t)(i * 32 + sr) * C_ + ss);
        }
        #pragma unroll
        for (int kk = 0; kk < 4; ++kk) {
            int i0 = kk * 32;
            bf16x8 bfr[8];
            #pragma unroll
            for (int nf = 0; nf < 8; ++nf)
                bfr[nf] = *(bf16x8*)&Bs[nf * 16 + l15][i0 + krow];
            bf16x8 a[2];
            if (XBF16 || sid > 0) {
                const bf16* src = XBF16 ? (sid == 0 ? xb : (sid == 1 ? tx1b : ub))
                                        : (sid == 1 ? tx1b : ub);
                #pragma unroll
                for (int mf = 0; mf < 2; ++mf)
                    a[mf] = *(const bf16x8*)(src + (size_t)row[mf] * TC_ + t * C_ + i0 + krow);
            } else {
                #pragma unroll
                for (int mf = 0; mf < 2; ++mf) {
                    const float* p = x + tslice + (size_t)row[mf] * C_ + i0 + krow;
                    f32x4 u0 = *(const f32x4*)p;
                    f32x4 u1 = *(const f32x4*)(p + 4);
                    bf16x8 av;
                    #pragma unroll
                    for (int j = 0; j < 4; ++j) { av[j] = bf16bits(u0[j]); av[j + 4] = bf16bits(u1[j]); }
                    a[mf] = av;
                }
            }
            #pragma unroll
            for (int mf = 0; mf < 2; ++mf)
                #pragma unroll
                for (int nf = 0; nf < 8; ++nf)
                    acc[mf][nf] = __builtin_amdgcn_mfma_f32_16x16x32_bf16(a[mf], bfr[nf], acc[mf][nf], 0, 0, 0);
        }
        __syncthreads();
        if (sid < 2) {
            #pragma unroll
            for (int i = 0; i < 4; ++i)
                *(int4*)&Bs[i * 32 + sr][ss] = pf[i];
            __syncthreads();
        }
    }

    const float* bs = bias + (size_t)t * C_;
    float* ot = out + tslice;
    #pragma unroll
    for (int nf = 0; nf < 8; ++nf) {
        int gc = nf * 16 + l15;
        float bv = bs[gc];
        #pragma unroll
        for (int mf = 0; mf < 2; ++mf) {
            #pragma unroll
            for (int reg = 0; reg < 4; ++reg) {
                int gr = m0 + wave * 32 + mf * 16 + l4 * 4 + reg;
                if (gr < N_) ot[(size_t)gr * C_ + gc] = acc[mf][nf][reg] + bv;
            }
        }
    }
}

// ---------------- launch ----------------

extern "C" void kernel_launch(void* const* d_in, const int* in_sizes, int n_in,
                              void* d_out, int out_size, void* d_ws, size_t ws_size,
                              hipStream_t stream) {
    const float* x      = (const float*)d_in[0];
    const int*   erow   = (const int*)d_in[1];
    const int*   ecol   = (const int*)d_in[2];
    const float* eval   = (const float*)d_in[3];
    const float* weight = (const float*)d_in[4];
    const float* bias   = (const float*)d_in[5];
    float* out = (float*)d_out;

    char* ws = (char*)d_ws;
    size_t off = 0;
    auto alloc = [&](size_t bytes) -> void* {
        void* p = ws + off;
        off += (bytes + 255) & ~(size_t)255;
        return p;
    };
    const size_t bufsz = (size_t)N_ * TC_ * sizeof(bf16);   // 51.2 MB
    int*  counts  = (int*)alloc((N_ + 1) * sizeof(int));
    int*  starts  = (int*)alloc((N_ + 1) * sizeof(int));
    int*  cursors = (int*)alloc((size_t)N_ * sizeof(int));
    int2* packed  = (int2*)alloc((size_t)E_ * sizeof(int2));
    bf16* Wt      = (bf16*)alloc((size_t)T_ * K_ * C_ * C_ * sizeof(bf16));
    bf16* bufX    = (bf16*)alloc(bufsz);   // xb (stays live in 3-buffer mode)
    bf16* bufT    = (bf16*)alloc(bufsz);   // tx1
    bool three = (ws_size >= off + bufsz + 256);
    bf16* bufU = three ? (bf16*)alloc(bufsz) : bufX;   // fallback: U overwrites xb

    hipMemsetAsync(counts, 0, (N_ + 1) * sizeof(int), stream);
    count_kernel<<<(E_ / 4 + 255) / 256, 256, 0, stream>>>(erow, counts);
    scan_kernel<<<1, 1024, 0, stream>>>(counts, starts, cursors);
    scatter_kernel<<<(E_ / 2 + 255) / 256, 256, 0, stream>>>(erow, ecol, eval, cursors, packed);
    prep_w_kernel<<<T_ * K_ * 16, 256, 0, stream>>>(weight, Wt);
    dim3 cg(N_ * 32 / 256, T_);
    convert_kernel<<<cg, 256, 0, stream>>>(x, bufX);
    spmm_kernel<<<N_, 128, 0, stream>>>(starts, packed, bufX, bufT);   // tx1 = S@xb
    spmm_kernel<<<N_, 128, 0, stream>>>(starts, packed, bufT, bufU);   // U = S@tx1
    dim3 g((N_ + GROWS_ - 1) / GROWS_, T_);
    if (three)
        gemm_kernel<1><<<g, 512, 0, stream>>>(x, bufX, bufT, bufU, Wt, bias, out);
    else
        gemm_kernel<0><<<g, 512, 0, stream>>>(x, bufX, bufT, bufU, Wt, bias, out);
}